// Round 6
// baseline (710.961 us; speedup 1.0000x reference)
//
#include <hip/hip_runtime.h>
#include <hip/hip_bf16.h>
#include <math.h>

#define NNODES 50000
#define HID    64
#define HEADS  4
#define FDIM   256   // HEADS*HID

typedef __attribute__((ext_vector_type(8))) short short8v;
typedef __attribute__((ext_vector_type(4))) float f32x4;

__device__ __forceinline__ float lrelu(float x) { return fmaxf(x, 0.2f * x); }

__device__ __forceinline__ ushort f2bf(float x) {
  union { float f; unsigned u; } c; c.f = x;
  unsigned r = (c.u + 0x7FFF + ((c.u >> 16) & 1)) >> 16;   // RNE
  return (ushort)r;
}
__device__ __forceinline__ float bf2f(ushort h) {
  union { unsigned u; float f; } c; c.u = ((unsigned)h) << 16;
  return c.f;
}

// ---------------- f32 -> (hi,lo) bf16 split, vectorized ----------------
__global__ void split_kernel(const float4* __restrict__ x, ushort* __restrict__ hi,
                             ushort* __restrict__ lo, int n4)
{
  int t = blockIdx.x * blockDim.x + threadIdx.x;
  if (t >= n4) return;
  float4 v = x[t];
  ushort h0 = f2bf(v.x), h1 = f2bf(v.y), h2 = f2bf(v.z), h3 = f2bf(v.w);
  *(ushort4*)(hi + (size_t)t * 4) = make_ushort4(h0, h1, h2, h3);
  *(ushort4*)(lo + (size_t)t * 4) = make_ushort4(
      f2bf(v.x - bf2f(h0)), f2bf(v.y - bf2f(h1)),
      f2bf(v.z - bf2f(h2)), f2bf(v.w - bf2f(h3)));
}

// ---------------- weight transposes+splits (rows 0..255 of cat arrays) ----------------
__global__ void wtconv_all_kernel(const float* __restrict__ enc_w, const float* __restrict__ g1_w,
                                  const float* __restrict__ g2_w, const float* __restrict__ lp1_w,
                                  ushort* __restrict__ we_hi, ushort* __restrict__ we_lo,
                                  ushort* __restrict__ w1_hi, ushort* __restrict__ w1_lo,
                                  ushort* __restrict__ w2_hi, ushort* __restrict__ w2_lo,
                                  ushort* __restrict__ wlp_hi, ushort* __restrict__ wlp_lo)
{
  int t = blockIdx.x * blockDim.x + threadIdx.x;   // 0..131071
  float w; ushort* dh; ushort* dl; int di;
  if (t < 16384) {                       // enc: N=64,K=256
    int n = t >> 8, k = t & 255;
    w = enc_w[(size_t)k * 64 + n]; dh = we_hi; dl = we_lo; di = t;
  } else if (t < 32768) {                // g1: N=256,K=64
    int l = t - 16384; int n = l >> 6, k = l & 63;
    w = g1_w[(size_t)k * 256 + n]; dh = w1_hi; dl = w1_lo; di = l;
  } else if (t < 98304) {                // g2: N=256,K=256
    int l = t - 32768; int n = l >> 8, k = l & 255;
    w = g2_w[(size_t)k * 256 + n]; dh = w2_hi; dl = w2_lo; di = l;
  } else {                               // lp stacked: N=128,K=256
    int l = t - 98304; int n = l >> 8, k = l & 255;
    int srow = (n < 64) ? k : (256 + k);
    w = lp1_w[(size_t)srow * 64 + (n & 63)]; dh = wlp_hi; dl = wlp_lo; di = l;
  }
  ushort h = f2bf(w);
  dh[di] = h;
  dl[di] = f2bf(w - bf2f(h));
}

// ---------------- att-combined columns: rows 256..271 of w1cat/w2cat ----------------
// row 256+j (j<4): W @ att_src blockdiag col j ; j in 4..7: att_dst; j in 8..15: zeros.
__global__ void attcomb_kernel(const float* __restrict__ g1_w, const float* __restrict__ g1_as,
                               const float* __restrict__ g1_ad,
                               const float* __restrict__ g2_w, const float* __restrict__ g2_as,
                               const float* __restrict__ g2_ad,
                               ushort* __restrict__ w1_hi, ushort* __restrict__ w1_lo,
                               ushort* __restrict__ w2_hi, ushort* __restrict__ w2_lo)
{
  int t = blockIdx.x * blockDim.x + threadIdx.x;   // 0..5119
  if (t < 1024) {                        // g1: KTOT=64
    int j = t >> 6, k = t & 63;
    float v = 0.f;
    if (j < 8) {
      int head = j & 3;
      const float* att = (j < 4 ? g1_as : g1_ad) + head * 64;
      for (int c = 0; c < 64; ++c) v += g1_w[(size_t)k * 256 + head * 64 + c] * att[c];
    }
    ushort h = f2bf(v);
    w1_hi[(256 + j) * 64 + k] = h;
    w1_lo[(256 + j) * 64 + k] = f2bf(v - bf2f(h));
  } else if (t < 5120) {                 // g2: KTOT=256
    int l = t - 1024; int j = l >> 8, k = l & 255;
    float v = 0.f;
    if (j < 8) {
      int head = j & 3;
      const float* att = (j < 4 ? g2_as : g2_ad) + head * 64;
      for (int c = 0; c < 64; ++c) v += g2_w[(size_t)k * 256 + head * 64 + c] * att[c];
    }
    ushort h = f2bf(v);
    w2_hi[(256 + j) * 256 + k] = h;
    w2_lo[(256 + j) * 256 + k] = f2bf(v - bf2f(h));
  }
}

// ---------------- MFMA GEMM v2: BM=64, full N per block, 3-pass bf16 ----------------
// OUTMODE 0: f32 out [M][Ntot]. OUTMODE 1: bias+relu, split hi/lo bf16 [M][Ntot].
// OUTMODE 2: plain bf16 [M][256] + (NFRAG==17) cols 256..263 -> a_s/a_d f32 [M][4].
template<int KTOT, int NFRAG, int OUTMODE>
__global__ __launch_bounds__(256) void mfma_gemm(
    const ushort* __restrict__ Ahi, const ushort* __restrict__ Alo,
    const ushort* __restrict__ Bhi, const ushort* __restrict__ Blo,
    const float* __restrict__ bias,
    float* __restrict__ outF, ushort* __restrict__ outHi, ushort* __restrict__ outLo,
    float* __restrict__ a_s, float* __restrict__ a_d,
    int M, int Ntot)
{
  __shared__ ushort AsH[64 * 64];
  __shared__ ushort AsL[64 * 64];
  const int tid  = threadIdx.x;
  const int lane = tid & 63;
  const int w    = tid >> 6;
  const int row0 = blockIdx.x * 64;

  f32x4 acc[NFRAG];
#pragma unroll
  for (int n = 0; n < NFRAG; ++n) acc[n] = (f32x4){0.f, 0.f, 0.f, 0.f};

  const int srow = w * 8 + (lane >> 3);          // 0..31
  const int ss   = (lane & 7) ^ (lane >> 3);     // swizzled k-slot (involution)
  const int gr0  = min(row0 + srow, M - 1);
  const int gr1  = min(row0 + srow + 32, M - 1);

  for (int kt = 0; kt < KTOT; kt += 64) {
    {
      const size_t go0 = (size_t)gr0 * KTOT + kt + ss * 8;
      const size_t go1 = (size_t)gr1 * KTOT + kt + ss * 8;
      __builtin_amdgcn_global_load_lds(
          (const __attribute__((address_space(1))) void*)(Ahi + go0),
          (__attribute__((address_space(3))) void*)(AsH + w * 512), 16, 0, 0);
      __builtin_amdgcn_global_load_lds(
          (const __attribute__((address_space(1))) void*)(Ahi + go1),
          (__attribute__((address_space(3))) void*)(AsH + 2048 + w * 512), 16, 0, 0);
      __builtin_amdgcn_global_load_lds(
          (const __attribute__((address_space(1))) void*)(Alo + go0),
          (__attribute__((address_space(3))) void*)(AsL + w * 512), 16, 0, 0);
      __builtin_amdgcn_global_load_lds(
          (const __attribute__((address_space(1))) void*)(Alo + go1),
          (__attribute__((address_space(3))) void*)(AsL + 2048 + w * 512), 16, 0, 0);
    }
    __syncthreads();

#pragma unroll
    for (int ks = 0; ks < 2; ++ks) {
      const int fr   = w * 16 + (lane & 15);
      const int sl   = (ks * 4 + (lane >> 4)) ^ (lane & 7);
      const int aidx = fr * 64 + sl * 8;
      const short8v ah = *(const short8v*)(AsH + aidx);
      const short8v al = *(const short8v*)(AsL + aidx);
#pragma unroll
      for (int nf = 0; nf < NFRAG; ++nf) {
        const size_t bo = (size_t)(nf * 16 + (lane & 15)) * KTOT + kt + ks * 32 + (lane >> 4) * 8;
        const short8v bh = *(const short8v*)(Bhi + bo);
        const short8v bl = *(const short8v*)(Blo + bo);
        acc[nf] = __builtin_amdgcn_mfma_f32_16x16x32_bf16(ah, bh, acc[nf], 0, 0, 0);
        acc[nf] = __builtin_amdgcn_mfma_f32_16x16x32_bf16(al, bh, acc[nf], 0, 0, 0);
        acc[nf] = __builtin_amdgcn_mfma_f32_16x16x32_bf16(ah, bl, acc[nf], 0, 0, 0);
      }
    }
    __syncthreads();
  }

  // epilogue: C/D layout col=lane&15, row=(lane>>4)*4+reg
  const int crow  = row0 + w * 16 + (lane >> 4) * 4;
  const int ccol0 = lane & 15;
#pragma unroll
  for (int nf = 0; nf < NFRAG; ++nf) {
    const int gcol = nf * 16 + ccol0;
#pragma unroll
    for (int r = 0; r < 4; ++r) {
      const int grow = crow + r;
      if (grow >= M) continue;
      float v = acc[nf][r];
      if (OUTMODE == 0) {
        outF[(size_t)grow * Ntot + gcol] = v;
      } else if (OUTMODE == 1) {
        v = fmaxf(v + bias[gcol], 0.f);
        const ushort h = f2bf(v);
        outHi[(size_t)grow * Ntot + gcol] = h;
        outLo[(size_t)grow * Ntot + gcol] = f2bf(v - bf2f(h));
      } else {
        if (nf < 16) {
          outHi[(size_t)grow * FDIM + gcol] = f2bf(v);
        } else if (NFRAG == 17) {
          const int c8 = ccol0;
          if (c8 < 4)      a_s[grow * 4 + c8] = v;
          else if (c8 < 8) a_d[grow * 4 + (c8 - 4)] = v;
        }
      }
    }
  }
}

// ---------------- CSR build ----------------
__global__ void hist_kernel(const int* __restrict__ dst, int* __restrict__ deg, int E)
{
  int i = blockIdx.x * blockDim.x + threadIdx.x;
  if (i < E) atomicAdd(&deg[dst[i]], 1);
}

__global__ void scan1_kernel(const int* __restrict__ deg, int* __restrict__ off,
                             int* __restrict__ bsum, int n)
{
  __shared__ int ws[4];
  const int t = threadIdx.x, lane = t & 63, w = t >> 6;
  const int i = blockIdx.x * 256 + t;
  const int v = (i < n) ? deg[i] : 0;
  int x = v;
#pragma unroll
  for (int d = 1; d < 64; d <<= 1) {
    int y = __shfl_up(x, d, 64);
    if (lane >= d) x += y;
  }
  if (lane == 63) ws[w] = x;
  __syncthreads();
  int add = 0;
  for (int k = 0; k < w; ++k) add += ws[k];
  if (i < n) off[i] = add + x - v;
  if (t == 255) bsum[blockIdx.x] = add + x;
}

__global__ void scan2_kernel(int* __restrict__ bsum, int nb)
{
  __shared__ int ws[4];
  const int t = threadIdx.x, lane = t & 63, w = t >> 6;
  const int v = (t < nb) ? bsum[t] : 0;
  int x = v;
#pragma unroll
  for (int d = 1; d < 64; d <<= 1) {
    int y = __shfl_up(x, d, 64);
    if (lane >= d) x += y;
  }
  if (lane == 63) ws[w] = x;
  __syncthreads();
  int add = 0;
  for (int k = 0; k < w; ++k) add += ws[k];
  if (t < nb) bsum[t] = add + x - v;
}

__global__ void scan3_kernel(int* __restrict__ off, const int* __restrict__ bsum, int n, int E)
{
  const int i = blockIdx.x * 256 + threadIdx.x;
  if (i < n) off[i] += bsum[blockIdx.x];
  if (i == 0) off[n] = E;
}

__global__ void scatter_kernel(const int* __restrict__ src, const int* __restrict__ dst,
                               const int* __restrict__ off, int* __restrict__ cursor,
                               int* __restrict__ sidx, int E)
{
  int i = blockIdx.x * blockDim.x + threadIdx.x;
  if (i < E) {
    int d = dst[i];
    int p = atomicAdd(&cursor[d], 1);
    sidx[off[d] + p] = src[i];
  }
}

// ---------------- GAT aggregation: one wave per dst node ----------------
__global__ __launch_bounds__(256) void aggregate_kernel(
    const ushort* __restrict__ hWb, const int* __restrict__ sidx,
    const int* __restrict__ off, const float* __restrict__ a_s, const float* __restrict__ a_d,
    const float* __restrict__ bias,
    ushort* __restrict__ outHi, ushort* __restrict__ outLo, int n_nodes)
{
  const int wid  = (blockIdx.x * 256 + threadIdx.x) >> 6;
  const int lane = threadIdx.x & 63;
  if (wid >= n_nodes) return;
  const int n = wid;
  const int beg = off[n], end = off[n + 1];

  // ---- Phase A: online (m, s) per head; lane covers edges beg+(lane>>2), step 16 ----
  const int hsel = lane & 3;
  const float adh = a_d[(unsigned)n * 4 + hsel];
  float m = -1e30f, ssum = 0.f;
  for (int j = beg + (lane >> 2); j < end; j += 16) {
    const unsigned s = (unsigned)sidx[j];
    const float e = lrelu(a_s[s * 4 + hsel] + adh);
    const float mn = fmaxf(m, e);
    ssum = ssum * __expf(m - mn) + __expf(e - mn);
    m = mn;
  }
#pragma unroll
  for (int d = 4; d < 64; d <<= 1) {
    const float mo = __shfl_xor(m, d, 64);
    const float so = __shfl_xor(ssum, d, 64);
    const float mn = fmaxf(m, mo);
    ssum = ssum * __expf(m - mn) + so * __expf(mo - mn);
    m = mn;
  }
  const int hb = lane >> 4;
  const float mh    = __shfl(m, hb, 64);
  const float sh    = __shfl(ssum, hb, 64);
  const float adh_b = __shfl(adh, hb, 64);

  // ---- Phase B ----
  float acc0 = 0.f, acc1 = 0.f, acc2 = 0.f, acc3 = 0.f;
  const unsigned lo4 = (unsigned)(lane << 2);
#pragma unroll 4
  for (int j = beg; j < end; ++j) {
    const unsigned s = (unsigned)sidx[j];
    const float e = lrelu(a_s[s * 4 + hb] + adh_b);
    const float wgt = __expf(e - mh);
    const ushort4 hv = *(const ushort4*)(hWb + s * (unsigned)FDIM + lo4);
    acc0 = fmaf(wgt, bf2f(hv.x), acc0);
    acc1 = fmaf(wgt, bf2f(hv.y), acc1);
    acc2 = fmaf(wgt, bf2f(hv.z), acc2);
    acc3 = fmaf(wgt, bf2f(hv.w), acc3);
  }
  const float inv = 1.f / (sh + 1e-16f);
  const float4 bv = *(const float4*)(bias + lo4);
  const float v0 = acc0 * inv + bv.x;
  const float v1 = acc1 * inv + bv.y;
  const float v2 = acc2 * inv + bv.z;
  const float v3 = acc3 * inv + bv.w;
  const ushort h0 = f2bf(v0), h1 = f2bf(v1), h2 = f2bf(v2), h3 = f2bf(v3);
  *(ushort4*)(outHi + (unsigned)n * FDIM + lo4) = make_ushort4(h0, h1, h2, h3);
  *(ushort4*)(outLo + (unsigned)n * FDIM + lo4) = make_ushort4(
      f2bf(v0 - bf2f(h0)), f2bf(v1 - bf2f(h1)),
      f2bf(v2 - bf2f(h2)), f2bf(v3 - bf2f(h3)));
}

// ---------------- link predictor: 16 pairs/block, 4 per wave ----------------
__global__ __launch_bounds__(256) void linkpred_kernel(
    const float* __restrict__ uv,
    const int* __restrict__ es, const int* __restrict__ ed,
    const float* __restrict__ b1, const float* __restrict__ w2, const float* __restrict__ b2,
    const float* __restrict__ w3, const float* __restrict__ b3,
    float* __restrict__ out, int n_eval)
{
  __shared__ float w2s[64 * 32];
  __shared__ float z1s[4][4][64];
  const int t = threadIdx.x;
  for (int i = t; i < 64 * 32; i += 256) w2s[i] = w2[i];
  const int w = t >> 6, lane = t & 63;
  const int pair0 = blockIdx.x * 16 + w * 4;
#pragma unroll
  for (int p = 0; p < 4; ++p) {
    const int pc = min(pair0 + p, n_eval - 1);
    const int s = es[pc], d = ed[pc];
    z1s[w][p][lane] = fmaxf(uv[(unsigned)s * 128 + lane] + uv[(unsigned)d * 128 + 64 + lane] + b1[lane], 0.f);
  }
  __syncthreads();
  const int half = lane >> 5;          // which pair of the pp-group
  const int col  = lane & 31;
  const float w3c = w3[col];
#pragma unroll
  for (int pp = 0; pp < 2; ++pp) {
    const int p = pp * 2 + half;
    float acc = b2[col];
#pragma unroll
    for (int k = 0; k < 64; ++k) acc = fmaf(z1s[w][p][k], w2s[k * 32 + col], acc);
    float zz = fmaxf(acc, 0.f) * w3c;
#pragma unroll
    for (int d = 1; d < 32; d <<= 1) zz += __shfl_xor(zz, d, 64);
    if (col == 0) {
      const int pv = pair0 + p;
      if (pv < n_eval) out[pv] = zz + b3[0];
    }
  }
}

// ---------------- launch ----------------
extern "C" void kernel_launch(void* const* d_in, const int* in_sizes, int n_in,
                              void* d_out, int out_size, void* d_ws, size_t ws_size,
                              hipStream_t stream)
{
  const float* x     = (const float*)d_in[0];
  const int*   ei    = (const int*)d_in[1];
  const int*   esrc  = (const int*)d_in[2];
  const int*   edst  = (const int*)d_in[3];
  const float* enc_w = (const float*)d_in[4];
  const float* enc_b = (const float*)d_in[5];
  const float* g1_w  = (const float*)d_in[6];
  const float* g1_as = (const float*)d_in[7];
  const float* g1_ad = (const float*)d_in[8];
  const float* g1_b  = (const float*)d_in[9];
  const float* g2_w  = (const float*)d_in[10];
  const float* g2_as = (const float*)d_in[11];
  const float* g2_ad = (const float*)d_in[12];
  const float* g2_b  = (const float*)d_in[13];
  const float* lp1_w = (const float*)d_in[14];
  const float* lp1_b = (const float*)d_in[15];
  const float* lp2_w = (const float*)d_in[16];
  const float* lp2_b = (const float*)d_in[17];
  const float* lp3_w = (const float*)d_in[18];
  const float* lp3_b = (const float*)d_in[19];
  float* out = (float*)d_out;

  const int E  = in_sizes[1] / 2;   // 1,000,000
  const int NE = in_sizes[2];       // 100,000
  const int M  = NNODES;
  const int NB = (M + 255) / 256;   // scan blocks

  const int* e_src = ei;
  const int* e_dst = ei + E;

  // ---- workspace layout ----
  ushort* hWb  = (ushort*)d_ws;                        // M*256 bf16 (aliased by uv later)
  float* a_s   = (float*)(hWb + (size_t)M * FDIM);     // M*4
  float* a_d   = a_s + (size_t)M * HEADS;              // M*4
  ushort* h_hi = (ushort*)(a_d + (size_t)M * HEADS);   // M*64
  ushort* h_lo = h_hi + (size_t)M * HID;
  ushort* agg_hi = h_lo + (size_t)M * HID;             // M*256 (also x_hi)
  ushort* agg_lo = agg_hi + (size_t)M * FDIM;          // (also x_lo)
  int*   deg    = (int*)(agg_lo + (size_t)M * FDIM);
  int*   cursor = deg + M;
  int*   off    = cursor + M;
  int*   bsum   = off + M + 1;                         // 256 ints
  int*   sidx   = bsum + 256;
  ushort* wb     = (ushort*)(sidx + E);
  ushort* we_hi  = wb;                  ushort* we_lo  = we_hi + 64 * 256;
  ushort* w1_hi  = we_lo + 64 * 256;    ushort* w1_lo  = w1_hi + 272 * 64;
  ushort* w2_hi  = w1_lo + 272 * 64;    ushort* w2_lo  = w2_hi + 272 * 256;
  ushort* wlp_hi = w2_lo + 272 * 256;   ushort* wlp_lo = wlp_hi + 128 * 256;
  ushort* x_hi = agg_hi;   // x planes dead after encoder
  ushort* x_lo = agg_lo;
  float* uv = (float*)hWb; // hWb dead after aggregate2; uv = M*128 f32

  // ---- CSR build ----
  hipMemsetAsync(deg, 0, sizeof(int) * 2 * (size_t)M, stream);
  hist_kernel<<<(E + 255) / 256, 256, 0, stream>>>(e_dst, deg, E);
  scan1_kernel<<<NB, 256, 0, stream>>>(deg, off, bsum, M);
  scan2_kernel<<<1, 256, 0, stream>>>(bsum, NB);
  scan3_kernel<<<NB, 256, 0, stream>>>(off, bsum, M, E);
  scatter_kernel<<<(E + 255) / 256, 256, 0, stream>>>(e_src, e_dst, off, cursor, sidx, E);

  // ---- conversions ----
  {
    int n4 = M * FDIM / 4;
    split_kernel<<<(n4 + 255) / 256, 256, 0, stream>>>((const float4*)x, x_hi, x_lo, n4);
    wtconv_all_kernel<<<512, 256, 0, stream>>>(enc_w, g1_w, g2_w, lp1_w,
                                               we_hi, we_lo, w1_hi, w1_lo,
                                               w2_hi, w2_lo, wlp_hi, wlp_lo);
    attcomb_kernel<<<20, 256, 0, stream>>>(g1_w, g1_as, g1_ad, g2_w, g2_as, g2_ad,
                                           w1_hi, w1_lo, w2_hi, w2_lo);
  }

  const int GB = (M + 63) / 64;   // 782 row-blocks

  // ---- encoder: h = relu(x @ enc_w + b) ----
  mfma_gemm<256, 4, 1><<<GB, 256, 0, stream>>>(
      x_hi, x_lo, we_hi, we_lo, enc_b, nullptr, h_hi, h_lo, nullptr, nullptr, M, HID);

  // ---- GAT layer 1: GEMM (+fused logits) + aggregate ----
  mfma_gemm<64, 17, 2><<<GB, 256, 0, stream>>>(
      h_hi, h_lo, w1_hi, w1_lo, nullptr, nullptr, hWb, nullptr, a_s, a_d, M, FDIM);
  aggregate_kernel<<<(M * 64 + 255) / 256, 256, 0, stream>>>(
      hWb, sidx, off, a_s, a_d, g1_b, agg_hi, agg_lo, M);

  // ---- GAT layer 2 ----
  mfma_gemm<256, 17, 2><<<GB, 256, 0, stream>>>(
      agg_hi, agg_lo, w2_hi, w2_lo, nullptr, nullptr, hWb, nullptr, a_s, a_d, M, FDIM);
  aggregate_kernel<<<(M * 64 + 255) / 256, 256, 0, stream>>>(
      hWb, sidx, off, a_s, a_d, g2_b, agg_hi, agg_lo, M);

  // ---- link predictor ----
  mfma_gemm<256, 8, 0><<<GB, 256, 0, stream>>>(
      agg_hi, agg_lo, wlp_hi, wlp_lo, nullptr, uv, nullptr, nullptr, nullptr, nullptr, M, 2 * HID);
  linkpred_kernel<<<(NE + 15) / 16, 256, 0, stream>>>(uv, esrc, edst, lp1_b, lp2_w, lp2_b,
                                                      lp3_w, lp3_b, out, NE);
}

// Round 7
// 614.117 us; speedup vs baseline: 1.1577x; 1.1577x over previous
//
#include <hip/hip_runtime.h>
#include <hip/hip_bf16.h>
#include <math.h>

#define NNODES 50000
#define HID    64
#define HEADS  4
#define FDIM   256   // HEADS*HID

typedef __attribute__((ext_vector_type(8))) short short8v;
typedef __attribute__((ext_vector_type(4))) float f32x4;

__device__ __forceinline__ float lrelu(float x) { return fmaxf(x, 0.2f * x); }

__device__ __forceinline__ ushort f2bf(float x) {
  union { float f; unsigned u; } c; c.f = x;
  unsigned r = (c.u + 0x7FFF + ((c.u >> 16) & 1)) >> 16;   // RNE
  return (ushort)r;
}
__device__ __forceinline__ float bf2f(ushort h) {
  union { unsigned u; float f; } c; c.u = ((unsigned)h) << 16;
  return c.f;
}

// ---------------- f32 -> (hi,lo) bf16 split, vectorized ----------------
__global__ void split_kernel(const float4* __restrict__ x, ushort* __restrict__ hi,
                             ushort* __restrict__ lo, int n4)
{
  int t = blockIdx.x * blockDim.x + threadIdx.x;
  if (t >= n4) return;
  float4 v = x[t];
  ushort h0 = f2bf(v.x), h1 = f2bf(v.y), h2 = f2bf(v.z), h3 = f2bf(v.w);
  *(ushort4*)(hi + (size_t)t * 4) = make_ushort4(h0, h1, h2, h3);
  *(ushort4*)(lo + (size_t)t * 4) = make_ushort4(
      f2bf(v.x - bf2f(h0)), f2bf(v.y - bf2f(h1)),
      f2bf(v.z - bf2f(h2)), f2bf(v.w - bf2f(h3)));
}

// ---------------- weight transposes+splits (rows 0..255 of cat arrays) ----------------
__global__ void wtconv_all_kernel(const float* __restrict__ enc_w, const float* __restrict__ g1_w,
                                  const float* __restrict__ g2_w, const float* __restrict__ lp1_w,
                                  ushort* __restrict__ we_hi, ushort* __restrict__ we_lo,
                                  ushort* __restrict__ w1_hi, ushort* __restrict__ w1_lo,
                                  ushort* __restrict__ w2_hi, ushort* __restrict__ w2_lo,
                                  ushort* __restrict__ wlp_hi, ushort* __restrict__ wlp_lo)
{
  int t = blockIdx.x * blockDim.x + threadIdx.x;   // 0..131071
  float w; ushort* dh; ushort* dl; int di;
  if (t < 16384) {                       // enc: N=64,K=256
    int n = t >> 8, k = t & 255;
    w = enc_w[(size_t)k * 64 + n]; dh = we_hi; dl = we_lo; di = t;
  } else if (t < 32768) {                // g1: N=256,K=64
    int l = t - 16384; int n = l >> 6, k = l & 63;
    w = g1_w[(size_t)k * 256 + n]; dh = w1_hi; dl = w1_lo; di = l;
  } else if (t < 98304) {                // g2: N=256,K=256
    int l = t - 32768; int n = l >> 8, k = l & 255;
    w = g2_w[(size_t)k * 256 + n]; dh = w2_hi; dl = w2_lo; di = l;
  } else {                               // lp stacked: N=128,K=256
    int l = t - 98304; int n = l >> 8, k = l & 255;
    int srow = (n < 64) ? k : (256 + k);
    w = lp1_w[(size_t)srow * 64 + (n & 63)]; dh = wlp_hi; dl = wlp_lo; di = l;
  }
  ushort h = f2bf(w);
  dh[di] = h;
  dl[di] = f2bf(w - bf2f(h));
}

// ---------------- att-combined columns: rows 256..271 of w1cat/w2cat ----------------
// row 256+j (j<4): W @ att_src blockdiag col j ; j in 4..7: att_dst; j in 8..15: zeros.
__global__ void attcomb_kernel(const float* __restrict__ g1_w, const float* __restrict__ g1_as,
                               const float* __restrict__ g1_ad,
                               const float* __restrict__ g2_w, const float* __restrict__ g2_as,
                               const float* __restrict__ g2_ad,
                               ushort* __restrict__ w1_hi, ushort* __restrict__ w1_lo,
                               ushort* __restrict__ w2_hi, ushort* __restrict__ w2_lo)
{
  int t = blockIdx.x * blockDim.x + threadIdx.x;   // 0..5119
  if (t < 1024) {                        // g1: KTOT=64
    int j = t >> 6, k = t & 63;
    float v = 0.f;
    if (j < 8) {
      int head = j & 3;
      const float* att = (j < 4 ? g1_as : g1_ad) + head * 64;
      for (int c = 0; c < 64; ++c) v += g1_w[(size_t)k * 256 + head * 64 + c] * att[c];
    }
    ushort h = f2bf(v);
    w1_hi[(256 + j) * 64 + k] = h;
    w1_lo[(256 + j) * 64 + k] = f2bf(v - bf2f(h));
  } else if (t < 5120) {                 // g2: KTOT=256
    int l = t - 1024; int j = l >> 8, k = l & 255;
    float v = 0.f;
    if (j < 8) {
      int head = j & 3;
      const float* att = (j < 4 ? g2_as : g2_ad) + head * 64;
      for (int c = 0; c < 64; ++c) v += g2_w[(size_t)k * 256 + head * 64 + c] * att[c];
    }
    ushort h = f2bf(v);
    w2_hi[(256 + j) * 256 + k] = h;
    w2_lo[(256 + j) * 256 + k] = f2bf(v - bf2f(h));
  }
}

// ---------------- MFMA GEMM (BM=128, BN=64/block): 3-pass bf16 ----------------
// grid = dim3(n_colblocks, GB): col-block is the FAST dim so blocks sharing an
// A-tile run concurrently (L2/L3 A-reuse). col0 = colbase + blockIdx.x*64.
// OUTMODE 0: f32 out [M][Ntot]. OUTMODE 1: bias+relu, split hi/lo bf16 [M][Ntot].
// OUTMODE 2: plain bf16 [M][256]; cols >=256 scatter into a_s/a_d f32 [M][4].
template<int KTOT, int NFRAG, int OUTMODE>
__global__ __launch_bounds__(256) void mfma_gemm(
    const ushort* __restrict__ Ahi, const ushort* __restrict__ Alo,
    const ushort* __restrict__ Bhi, const ushort* __restrict__ Blo,
    const float* __restrict__ bias,
    float* __restrict__ outF, ushort* __restrict__ outHi, ushort* __restrict__ outLo,
    float* __restrict__ a_s, float* __restrict__ a_d,
    int M, int Ntot, int colbase)
{
  __shared__ ushort AsH[128 * 64];
  __shared__ ushort AsL[128 * 64];
  const int tid  = threadIdx.x;
  const int lane = tid & 63;
  const int wid  = tid >> 6;
  const int row0 = blockIdx.y * 128;
  const int col0 = colbase + blockIdx.x * 64;

  f32x4 acc[2][NFRAG];
#pragma unroll
  for (int m = 0; m < 2; ++m)
#pragma unroll
    for (int n = 0; n < NFRAG; ++n) acc[m][n] = (f32x4){0.f, 0.f, 0.f, 0.f};

  const int rsub = lane >> 3;   // row within 8-row chunk
  const int slot = lane & 7;    // 16B slot within 128B LDS row
  const int brow = col0 + (lane & 15);
  const int bk   = (lane >> 4) * 8;

  for (int kt = 0; kt < KTOT; kt += 64) {
    // ---- stage A tile (hi+lo): 16 chunks of 8 rows x 128B, swizzled source ----
#pragma unroll
    for (int i = 0; i < 4; ++i) {
      const int c  = i * 4 + wid;
      const int r  = c * 8 + rsub;
      const int gr = min(row0 + r, M - 1);
      const int ss = slot ^ rsub;                       // involution swizzle (T2)
      const size_t goff = (size_t)gr * KTOT + kt + ss * 8;
      __builtin_amdgcn_global_load_lds(
          (const __attribute__((address_space(1))) void*)(Ahi + goff),
          (__attribute__((address_space(3))) void*)(AsH + c * 512), 16, 0, 0);
      __builtin_amdgcn_global_load_lds(
          (const __attribute__((address_space(1))) void*)(Alo + goff),
          (__attribute__((address_space(3))) void*)(AsL + c * 512), 16, 0, 0);
    }
    __syncthreads();

#pragma unroll
    for (int ks = 0; ks < 2; ++ks) {
      short8v ah[2], al[2], bh[NFRAG], bl[NFRAG];
#pragma unroll
      for (int mf = 0; mf < 2; ++mf) {
        const int r   = wid * 32 + mf * 16 + (lane & 15);
        const int sl  = (ks * 4 + (lane >> 4)) ^ (r & 7);
        const int idx = r * 64 + sl * 8;
        ah[mf] = *(const short8v*)(AsH + idx);
        al[mf] = *(const short8v*)(AsL + idx);
      }
#pragma unroll
      for (int nf = 0; nf < NFRAG; ++nf) {
        const size_t bo = (size_t)(brow + nf * 16) * KTOT + kt + ks * 32 + bk;
        bh[nf] = *(const short8v*)(Bhi + bo);
        bl[nf] = *(const short8v*)(Blo + bo);
      }
#pragma unroll
      for (int mf = 0; mf < 2; ++mf)
#pragma unroll
        for (int nf = 0; nf < NFRAG; ++nf) {
          acc[mf][nf] = __builtin_amdgcn_mfma_f32_16x16x32_bf16(ah[mf], bh[nf], acc[mf][nf], 0, 0, 0);
          acc[mf][nf] = __builtin_amdgcn_mfma_f32_16x16x32_bf16(al[mf], bh[nf], acc[mf][nf], 0, 0, 0);
          acc[mf][nf] = __builtin_amdgcn_mfma_f32_16x16x32_bf16(ah[mf], bl[nf], acc[mf][nf], 0, 0, 0);
        }
    }
    __syncthreads();
  }

  // ---- epilogue: C/D frag layout col=lane&15, row=(lane>>4)*4+reg ----
  const int crow = row0 + wid * 32 + (lane >> 4) * 4;
  const int ccol = col0 + (lane & 15);
#pragma unroll
  for (int mf = 0; mf < 2; ++mf)
#pragma unroll
    for (int nf = 0; nf < NFRAG; ++nf)
#pragma unroll
      for (int r = 0; r < 4; ++r) {
        const int grow = crow + mf * 16 + r;
        const int gcol = ccol + nf * 16;
        if (grow >= M) continue;
        float v = acc[mf][nf][r];
        if (OUTMODE == 0) {
          outF[(size_t)grow * Ntot + gcol] = v;
        } else if (OUTMODE == 1) {
          v = fmaxf(v + bias[gcol], 0.f);
          const ushort h = f2bf(v);
          outHi[(size_t)grow * Ntot + gcol] = h;
          outLo[(size_t)grow * Ntot + gcol] = f2bf(v - bf2f(h));
        } else {
          if (gcol < 256) {
            outHi[(size_t)grow * FDIM + gcol] = f2bf(v);
          } else {
            const int c8 = gcol - 256;
            if (c8 < 4)      a_s[grow * 4 + c8] = v;
            else if (c8 < 8) a_d[grow * 4 + (c8 - 4)] = v;
          }
        }
      }
}

// ---------------- CSR build ----------------
__global__ void hist_kernel(const int* __restrict__ dst, int* __restrict__ deg, int E)
{
  int i = blockIdx.x * blockDim.x + threadIdx.x;
  if (i < E) atomicAdd(&deg[dst[i]], 1);
}

__global__ void scan1_kernel(const int* __restrict__ deg, int* __restrict__ off,
                             int* __restrict__ bsum, int n)
{
  __shared__ int ws[4];
  const int t = threadIdx.x, lane = t & 63, w = t >> 6;
  const int i = blockIdx.x * 256 + t;
  const int v = (i < n) ? deg[i] : 0;
  int x = v;
#pragma unroll
  for (int d = 1; d < 64; d <<= 1) {
    int y = __shfl_up(x, d, 64);
    if (lane >= d) x += y;
  }
  if (lane == 63) ws[w] = x;
  __syncthreads();
  int add = 0;
  for (int k = 0; k < w; ++k) add += ws[k];
  if (i < n) off[i] = add + x - v;
  if (t == 255) bsum[blockIdx.x] = add + x;
}

__global__ void scan2_kernel(int* __restrict__ bsum, int nb)
{
  __shared__ int ws[4];
  const int t = threadIdx.x, lane = t & 63, w = t >> 6;
  const int v = (t < nb) ? bsum[t] : 0;
  int x = v;
#pragma unroll
  for (int d = 1; d < 64; d <<= 1) {
    int y = __shfl_up(x, d, 64);
    if (lane >= d) x += y;
  }
  if (lane == 63) ws[w] = x;
  __syncthreads();
  int add = 0;
  for (int k = 0; k < w; ++k) add += ws[k];
  if (t < nb) bsum[t] = add + x - v;
}

__global__ void scan3_kernel(int* __restrict__ off, const int* __restrict__ bsum, int n, int E)
{
  const int i = blockIdx.x * 256 + threadIdx.x;
  if (i < n) off[i] += bsum[blockIdx.x];
  if (i == 0) off[n] = E;
}

__global__ void scatter_kernel(const int* __restrict__ src, const int* __restrict__ dst,
                               const int* __restrict__ off, int* __restrict__ cursor,
                               int* __restrict__ sidx, int E)
{
  int i = blockIdx.x * blockDim.x + threadIdx.x;
  if (i < E) {
    int d = dst[i];
    int p = atomicAdd(&cursor[d], 1);
    sidx[off[d] + p] = src[i];
  }
}

// ---------------- GAT aggregation: one wave per dst node ----------------
__global__ __launch_bounds__(256) void aggregate_kernel(
    const ushort* __restrict__ hWb, const int* __restrict__ sidx,
    const int* __restrict__ off, const float* __restrict__ a_s, const float* __restrict__ a_d,
    const float* __restrict__ bias,
    ushort* __restrict__ outHi, ushort* __restrict__ outLo, int n_nodes)
{
  const int wid  = (blockIdx.x * 256 + threadIdx.x) >> 6;
  const int lane = threadIdx.x & 63;
  if (wid >= n_nodes) return;
  const int n = wid;
  const int beg = off[n], end = off[n + 1];

  // ---- Phase A: online (m, s) per head ----
  const int hsel = lane & 3;
  const float adh = a_d[(unsigned)n * 4 + hsel];
  float m = -1e30f, ssum = 0.f;
  for (int j = beg + (lane >> 2); j < end; j += 16) {
    const unsigned s = (unsigned)sidx[j];
    const float e = lrelu(a_s[s * 4 + hsel] + adh);
    const float mn = fmaxf(m, e);
    ssum = ssum * __expf(m - mn) + __expf(e - mn);
    m = mn;
  }
#pragma unroll
  for (int d = 4; d < 64; d <<= 1) {
    const float mo = __shfl_xor(m, d, 64);
    const float so = __shfl_xor(ssum, d, 64);
    const float mn = fmaxf(m, mo);
    ssum = ssum * __expf(m - mn) + so * __expf(mo - mn);
    m = mn;
  }
  const int hb = lane >> 4;
  const float mh    = __shfl(m, hb, 64);
  const float sh    = __shfl(ssum, hb, 64);
  const float adh_b = __shfl(adh, hb, 64);

  // ---- Phase B ----
  float acc0 = 0.f, acc1 = 0.f, acc2 = 0.f, acc3 = 0.f;
  const unsigned lo4 = (unsigned)(lane << 2);
#pragma unroll 4
  for (int j = beg; j < end; ++j) {
    const unsigned s = (unsigned)sidx[j];
    const float e = lrelu(a_s[s * 4 + hb] + adh_b);
    const float wgt = __expf(e - mh);
    const ushort4 hv = *(const ushort4*)(hWb + s * (unsigned)FDIM + lo4);
    acc0 = fmaf(wgt, bf2f(hv.x), acc0);
    acc1 = fmaf(wgt, bf2f(hv.y), acc1);
    acc2 = fmaf(wgt, bf2f(hv.z), acc2);
    acc3 = fmaf(wgt, bf2f(hv.w), acc3);
  }
  const float inv = 1.f / (sh + 1e-16f);
  const float4 bv = *(const float4*)(bias + lo4);
  const float v0 = acc0 * inv + bv.x;
  const float v1 = acc1 * inv + bv.y;
  const float v2 = acc2 * inv + bv.z;
  const float v3 = acc3 * inv + bv.w;
  const ushort h0 = f2bf(v0), h1 = f2bf(v1), h2 = f2bf(v2), h3 = f2bf(v3);
  *(ushort4*)(outHi + (unsigned)n * FDIM + lo4) = make_ushort4(h0, h1, h2, h3);
  *(ushort4*)(outLo + (unsigned)n * FDIM + lo4) = make_ushort4(
      f2bf(v0 - bf2f(h0)), f2bf(v1 - bf2f(h1)),
      f2bf(v2 - bf2f(h2)), f2bf(v3 - bf2f(h3)));
}

// ---------------- link predictor: 16 pairs/block, 4 per wave ----------------
__global__ __launch_bounds__(256) void linkpred_kernel(
    const float* __restrict__ uv,
    const int* __restrict__ es, const int* __restrict__ ed,
    const float* __restrict__ b1, const float* __restrict__ w2, const float* __restrict__ b2,
    const float* __restrict__ w3, const float* __restrict__ b3,
    float* __restrict__ out, int n_eval)
{
  __shared__ float w2s[64 * 32];
  __shared__ float z1s[4][4][64];
  const int t = threadIdx.x;
  for (int i = t; i < 64 * 32; i += 256) w2s[i] = w2[i];
  const int w = t >> 6, lane = t & 63;
  const int pair0 = blockIdx.x * 16 + w * 4;
#pragma unroll
  for (int p = 0; p < 4; ++p) {
    const int pc = min(pair0 + p, n_eval - 1);
    const int s = es[pc], d = ed[pc];
    z1s[w][p][lane] = fmaxf(uv[(unsigned)s * 128 + lane] + uv[(unsigned)d * 128 + 64 + lane] + b1[lane], 0.f);
  }
  __syncthreads();
  const int half = lane >> 5;
  const int col  = lane & 31;
  const float w3c = w3[col];
#pragma unroll
  for (int pp = 0; pp < 2; ++pp) {
    const int p = pp * 2 + half;
    float acc = b2[col];
#pragma unroll
    for (int k = 0; k < 64; ++k) acc = fmaf(z1s[w][p][k], w2s[k * 32 + col], acc);
    float zz = fmaxf(acc, 0.f) * w3c;
#pragma unroll
    for (int d = 1; d < 32; d <<= 1) zz += __shfl_xor(zz, d, 64);
    if (col == 0) {
      const int pv = pair0 + p;
      if (pv < n_eval) out[pv] = zz + b3[0];
    }
  }
}

// ---------------- launch ----------------
extern "C" void kernel_launch(void* const* d_in, const int* in_sizes, int n_in,
                              void* d_out, int out_size, void* d_ws, size_t ws_size,
                              hipStream_t stream)
{
  const float* x     = (const float*)d_in[0];
  const int*   ei    = (const int*)d_in[1];
  const int*   esrc  = (const int*)d_in[2];
  const int*   edst  = (const int*)d_in[3];
  const float* enc_w = (const float*)d_in[4];
  const float* enc_b = (const float*)d_in[5];
  const float* g1_w  = (const float*)d_in[6];
  const float* g1_as = (const float*)d_in[7];
  const float* g1_ad = (const float*)d_in[8];
  const float* g1_b  = (const float*)d_in[9];
  const float* g2_w  = (const float*)d_in[10];
  const float* g2_as = (const float*)d_in[11];
  const float* g2_ad = (const float*)d_in[12];
  const float* g2_b  = (const float*)d_in[13];
  const float* lp1_w = (const float*)d_in[14];
  const float* lp1_b = (const float*)d_in[15];
  const float* lp2_w = (const float*)d_in[16];
  const float* lp2_b = (const float*)d_in[17];
  const float* lp3_w = (const float*)d_in[18];
  const float* lp3_b = (const float*)d_in[19];
  float* out = (float*)d_out;

  const int E  = in_sizes[1] / 2;   // 1,000,000
  const int NE = in_sizes[2];       // 100,000
  const int M  = NNODES;
  const int NB = (M + 255) / 256;   // scan blocks

  const int* e_src = ei;
  const int* e_dst = ei + E;

  // ---- workspace layout ----
  ushort* hWb  = (ushort*)d_ws;                        // M*256 bf16 (aliased by uv later)
  float* a_s   = (float*)(hWb + (size_t)M * FDIM);     // M*4
  float* a_d   = a_s + (size_t)M * HEADS;              // M*4
  ushort* h_hi = (ushort*)(a_d + (size_t)M * HEADS);   // M*64
  ushort* h_lo = h_hi + (size_t)M * HID;
  ushort* agg_hi = h_lo + (size_t)M * HID;             // M*256 (also x_hi)
  ushort* agg_lo = agg_hi + (size_t)M * FDIM;          // (also x_lo)
  int*   deg    = (int*)(agg_lo + (size_t)M * FDIM);
  int*   cursor = deg + M;
  int*   off    = cursor + M;
  int*   bsum   = off + M + 1;                         // 256 ints
  int*   sidx   = bsum + 256;
  ushort* wb     = (ushort*)(sidx + E);
  ushort* we_hi  = wb;                  ushort* we_lo  = we_hi + 64 * 256;
  ushort* w1_hi  = we_lo + 64 * 256;    ushort* w1_lo  = w1_hi + 272 * 64;
  ushort* w2_hi  = w1_lo + 272 * 64;    ushort* w2_lo  = w2_hi + 272 * 256;
  ushort* wlp_hi = w2_lo + 272 * 256;   ushort* wlp_lo = wlp_hi + 128 * 256;
  ushort* x_hi = agg_hi;   // x planes dead after encoder
  ushort* x_lo = agg_lo;
  float* uv = (float*)hWb; // hWb dead after aggregate2; uv = M*128 f32

  // ---- CSR build ----
  hipMemsetAsync(deg, 0, sizeof(int) * 2 * (size_t)M, stream);
  hist_kernel<<<(E + 255) / 256, 256, 0, stream>>>(e_dst, deg, E);
  scan1_kernel<<<NB, 256, 0, stream>>>(deg, off, bsum, M);
  scan2_kernel<<<1, 256, 0, stream>>>(bsum, NB);
  scan3_kernel<<<NB, 256, 0, stream>>>(off, bsum, M, E);
  scatter_kernel<<<(E + 255) / 256, 256, 0, stream>>>(e_src, e_dst, off, cursor, sidx, E);

  // ---- conversions ----
  {
    int n4 = M * FDIM / 4;
    split_kernel<<<(n4 + 255) / 256, 256, 0, stream>>>((const float4*)x, x_hi, x_lo, n4);
    wtconv_all_kernel<<<512, 256, 0, stream>>>(enc_w, g1_w, g2_w, lp1_w,
                                               we_hi, we_lo, w1_hi, w1_lo,
                                               w2_hi, w2_lo, wlp_hi, wlp_lo);
    attcomb_kernel<<<20, 256, 0, stream>>>(g1_w, g1_as, g1_ad, g2_w, g2_as, g2_ad,
                                           w1_hi, w1_lo, w2_hi, w2_lo);
  }

  const int GB = (M + 127) / 128;   // 391 row-blocks

  // ---- encoder: h = relu(x @ enc_w + b) ----
  mfma_gemm<256, 4, 1><<<dim3(1, GB), 256, 0, stream>>>(
      x_hi, x_lo, we_hi, we_lo, enc_b, nullptr, h_hi, h_lo, nullptr, nullptr, M, HID, 0);

  // ---- GAT layer 1: GEMM cols 0..191, then cols 192..271 (incl. fused logits) ----
  mfma_gemm<64, 4, 2><<<dim3(3, GB), 256, 0, stream>>>(
      h_hi, h_lo, w1_hi, w1_lo, nullptr, nullptr, hWb, nullptr, a_s, a_d, M, FDIM, 0);
  mfma_gemm<64, 5, 2><<<dim3(1, GB), 256, 0, stream>>>(
      h_hi, h_lo, w1_hi, w1_lo, nullptr, nullptr, hWb, nullptr, a_s, a_d, M, FDIM, 192);
  aggregate_kernel<<<(M * 64 + 255) / 256, 256, 0, stream>>>(
      hWb, sidx, off, a_s, a_d, g1_b, agg_hi, agg_lo, M);

  // ---- GAT layer 2 ----
  mfma_gemm<256, 4, 2><<<dim3(3, GB), 256, 0, stream>>>(
      agg_hi, agg_lo, w2_hi, w2_lo, nullptr, nullptr, hWb, nullptr, a_s, a_d, M, FDIM, 0);
  mfma_gemm<256, 5, 2><<<dim3(1, GB), 256, 0, stream>>>(
      agg_hi, agg_lo, w2_hi, w2_lo, nullptr, nullptr, hWb, nullptr, a_s, a_d, M, FDIM, 192);
  aggregate_kernel<<<(M * 64 + 255) / 256, 256, 0, stream>>>(
      hWb, sidx, off, a_s, a_d, g2_b, agg_hi, agg_lo, M);

  // ---- link predictor ----
  mfma_gemm<256, 4, 0><<<dim3(2, GB), 256, 0, stream>>>(
      agg_hi, agg_lo, wlp_hi, wlp_lo, nullptr, uv, nullptr, nullptr, nullptr, nullptr, M, 2 * HID, 0);
  linkpred_kernel<<<(NE + 15) / 16, 256, 0, stream>>>(uv, esrc, edst, lp1_b, lp2_w, lp2_b,
                                                      lp3_w, lp3_b, out, NE);
}